// Round 1
// baseline (9.733 us; speedup 1.0000x reference)
//
#include <hip/hip_runtime.h>

// QuantumLayer: 4-qubit RX(x)/RY(w) + CNOT chain + <Z_i> readout.
// Analytic identity: out[b][i] = prod_{j<=i} cos(x[b][j]) * cos(w[j]).
// Derivation: pre-CNOT state is a product state with per-qubit
// <Z_j> = cos(x_j)cos(w_j); Heisenberg conjugation of Z_i through the
// CNOT(0,1),CNOT(1,2),CNOT(2,3) chain yields Z_0...Z_i, whose product-state
// expectation factorizes.

__global__ void __launch_bounds__(256)
QuantumLayer_56607668961323_kernel(const float4* __restrict__ x,
                                   const float* __restrict__ w,
                                   float4* __restrict__ out,
                                   int n) {
    int i = blockIdx.x * blockDim.x + threadIdx.x;
    if (i >= n) return;

    // weights are wave-uniform: scalar loads, cached; 4 extra cosf is noise.
    float cw0 = cosf(w[0]);
    float cw1 = cosf(w[1]);
    float cw2 = cosf(w[2]);
    float cw3 = cosf(w[3]);

    float4 xv = x[i];
    float z0 = cosf(xv.x) * cw0;
    float z1 = z0 * cosf(xv.y) * cw1;
    float z2 = z1 * cosf(xv.z) * cw2;
    float z3 = z2 * cosf(xv.w) * cw3;

    out[i] = make_float4(z0, z1, z2, z3);
}

extern "C" void kernel_launch(void* const* d_in, const int* in_sizes, int n_in,
                              void* d_out, int out_size, void* d_ws, size_t ws_size,
                              hipStream_t stream) {
    const float4* x = (const float4*)d_in[0];   // (BATCH, 4) f32, read as float4
    const float*  w = (const float*)d_in[1];    // (4,) f32
    float4* out = (float4*)d_out;               // (BATCH, 4) f32, written as float4

    int n = in_sizes[0] / 4;                    // BATCH elements
    int block = 256;
    int grid = (n + block - 1) / block;
    QuantumLayer_56607668961323_kernel<<<grid, block, 0, stream>>>(x, w, out, n);
}